// Round 1
// baseline (3240.264 us; speedup 1.0000x reference)
//
#include <hip/hip_runtime.h>
#include <hip/hip_bf16.h>
#include <cmath>

static constexpr int HN = 12;      // heads
static constexpr int DHEAD = 64;   // head dim
static constexpr int DMODEL = 768;
static constexpr int NQ = 1024;    // seq len (q == k)
static constexpr int NB = 4;       // batch

// C = A(MxK) @ W(KxN) + bias
// LAYOUT 0: C[m*N + c]   (row-major)
// LAYOUT 1: C[((b*HN + h)*NQ + n)*64 + d]  with m=b*NQ+n, c=h*64+d (head-major)
template<int LAYOUT>
__global__ __launch_bounds__(256)
void gemm_f32(const float* __restrict__ A, const float* __restrict__ W,
              const float* __restrict__ bias, float* __restrict__ C,
              int M, int N, int K)
{
    __shared__ float As[16][65];   // [k][m], padded to break bank conflicts
    __shared__ float Bs[16][64];   // [k][n]
    const int tid = threadIdx.x;
    const int bm = blockIdx.y * 64;
    const int bn = blockIdx.x * 64;
    const int tx = tid & 15, ty = tid >> 4;
    float acc[4][4] = {};
    for (int k0 = 0; k0 < K; k0 += 16) {
        #pragma unroll
        for (int l = 0; l < 4; ++l) {          // A tile: 64 rows x 16 k
            int idx = tid + l * 256;
            int r = idx >> 4, kk = idx & 15;
            As[kk][r] = A[(size_t)(bm + r) * K + k0 + kk];
        }
        #pragma unroll
        for (int l = 0; l < 4; ++l) {          // B tile: 16 k x 64 cols
            int idx = tid + l * 256;
            int kk = idx >> 6, c = idx & 63;
            Bs[kk][c] = W[(size_t)(k0 + kk) * N + bn + c];
        }
        __syncthreads();
        #pragma unroll
        for (int kk = 0; kk < 16; ++kk) {
            float a[4], b[4];
            #pragma unroll
            for (int i = 0; i < 4; ++i) a[i] = As[kk][ty * 4 + i];
            #pragma unroll
            for (int j = 0; j < 4; ++j) b[j] = Bs[kk][tx * 4 + j];
            #pragma unroll
            for (int i = 0; i < 4; ++i)
                #pragma unroll
                for (int j = 0; j < 4; ++j)
                    acc[i][j] += a[i] * b[j];
        }
        __syncthreads();
    }
    #pragma unroll
    for (int i = 0; i < 4; ++i) {
        int m = bm + ty * 4 + i;
        #pragma unroll
        for (int j = 0; j < 4; ++j) {
            int c = bn + tx * 4 + j;
            float val = acc[i][j] + bias[c];
            if (LAYOUT == 0) {
                C[(size_t)m * N + c] = val;
            } else {
                int b = m >> 10, n = m & (NQ - 1);
                int h = c >> 6, d = c & 63;
                C[(((size_t)(b * HN + h)) * NQ + n) * DHEAD + d] = val;
            }
        }
    }
}

// One block (256 threads) per (b, h, q-row).
__global__ __launch_bounds__(256)
void attn_f32(const float* __restrict__ q, const float* __restrict__ k,
              const float* __restrict__ v, const float* __restrict__ aw,
              const int* __restrict__ mask, const float* __restrict__ lm,
              float* __restrict__ out)
{
    const int qi = blockIdx.x;
    const int h  = blockIdx.y;
    const int b  = blockIdx.z;
    const int tid = threadIdx.x;
    __shared__ float qs[64];
    __shared__ float sc[1024];
    __shared__ float red[256];
    const size_t bh  = ((size_t)(b * HN + h)) * NQ * DHEAD;        // k/v base
    const size_t awb = (((size_t)(b * HN + h)) * NQ + qi) * NQ;    // aw/mask row
    if (tid < 64) qs[tid] = q[bh + (size_t)qi * DHEAD + tid];
    __syncthreads();

    // scores
    float lmax = -INFINITY;
    #pragma unroll
    for (int l = 0; l < 4; ++l) {
        int j = tid + l * 256;
        const float4* kp4 = reinterpret_cast<const float4*>(k + bh + (size_t)j * DHEAD);
        float s = 0.f;
        #pragma unroll
        for (int d4 = 0; d4 < 16; ++d4) {
            float4 kv = kp4[d4];
            s += qs[d4 * 4 + 0] * kv.x + qs[d4 * 4 + 1] * kv.y
               + qs[d4 * 4 + 2] * kv.z + qs[d4 * 4 + 3] * kv.w;
        }
        s *= 0.125f;                    // 1/sqrt(64)
        s *= aw[awb + j];               // multiplicative weight (before mask)
        if (mask[awb + j]) s = -INFINITY;
        s += lm[((size_t)b * NQ + j) * HN + h];   // additive bias (after mask)
        sc[j] = s;
        lmax = fmaxf(lmax, s);
    }
    red[tid] = lmax; __syncthreads();
    for (int s2 = 128; s2 > 0; s2 >>= 1) {
        if (tid < s2) red[tid] = fmaxf(red[tid], red[tid + s2]);
        __syncthreads();
    }
    const float mx = red[0];
    __syncthreads();

    // exp + sum
    float lsum = 0.f;
    #pragma unroll
    for (int l = 0; l < 4; ++l) {
        int j = tid + l * 256;
        float p = __expf(sc[j] - mx);
        sc[j] = p;
        lsum += p;
    }
    red[tid] = lsum; __syncthreads();
    for (int s2 = 128; s2 > 0; s2 >>= 1) {
        if (tid < s2) red[tid] += red[tid + s2];
        __syncthreads();
    }
    const float inv = 1.f / red[0];
    __syncthreads();

    // PV: thread = (chunk of 256 keys, output dim d)
    const int d = tid & 63;
    const int chunk = tid >> 6;
    float acc = 0.f;
    const float* vp = v + bh + (size_t)chunk * 256 * DHEAD + d;
    #pragma unroll 4
    for (int j = 0; j < 256; ++j)
        acc += sc[chunk * 256 + j] * vp[(size_t)j * DHEAD];
    red[tid] = acc; __syncthreads();
    if (tid < 128) red[tid] += red[tid + 128];
    __syncthreads();
    if (tid < 64) {
        float o = (red[tid] + red[tid + 64]) * inv;
        out[((size_t)(b * NQ + qi)) * DMODEL + h * DHEAD + tid] = o;
    }
}

extern "C" void kernel_launch(void* const* d_in, const int* in_sizes, int n_in,
                              void* d_out, int out_size, void* d_ws, size_t ws_size,
                              hipStream_t stream)
{
    const float* queries = (const float*)d_in[0];
    const float* keys    = (const float*)d_in[1];
    const float* values  = (const float*)d_in[2];
    const float* lossmap = (const float*)d_in[3];
    const int*   mask    = (const int*)d_in[4];   // bool in ref -> int32 on device (assumed)
    const float* aw      = (const float*)d_in[5];
    const float* Wq = (const float*)d_in[6];
    const float* bq = (const float*)d_in[7];
    const float* Wk = (const float*)d_in[8];
    const float* bk = (const float*)d_in[9];
    const float* Wv = (const float*)d_in[10];
    const float* bv = (const float*)d_in[11];
    const float* Wo = (const float*)d_in[12];
    const float* bo = (const float*)d_in[13];
    float* outp = (float*)d_out;

    const size_t per = (size_t)NB * HN * NQ * DHEAD;  // 3,145,728 floats
    float* qws = (float*)d_ws;
    float* kws = qws + per;
    float* vws = kws + per;
    float* ows = vws + per;

    const int M = NB * NQ;  // 4096
    dim3 gg(DMODEL / 64, M / 64), gb(256);
    gemm_f32<1><<<gg, gb, 0, stream>>>(queries, Wq, bq, qws, M, DMODEL, DMODEL);
    gemm_f32<1><<<gg, gb, 0, stream>>>(keys,    Wk, bk, kws, M, DMODEL, DMODEL);
    gemm_f32<1><<<gg, gb, 0, stream>>>(values,  Wv, bv, vws, M, DMODEL, DMODEL);
    attn_f32<<<dim3(NQ, HN, NB), 256, 0, stream>>>(qws, kws, vws, aw, mask, lossmap, ows);
    gemm_f32<0><<<gg, gb, 0, stream>>>(ows, Wo, bo, outp, M, DMODEL, DMODEL);
}

// Round 2
// 542.504 us; speedup vs baseline: 5.9728x; 5.9728x over previous
//
#include <hip/hip_runtime.h>
#include <hip/hip_bf16.h>
#include <cmath>

static constexpr int HN = 12;      // heads
static constexpr int DHEAD = 64;   // head dim
static constexpr int DMODEL = 768;
static constexpr int NQ = 1024;    // seq len (q == k)
static constexpr int NB = 4;       // batch

typedef __attribute__((ext_vector_type(8))) short bf16x8;
typedef __attribute__((ext_vector_type(4))) float f32x4;

static __device__ __forceinline__ unsigned short f2bf(float f) {
    unsigned int u = __builtin_bit_cast(unsigned int, f);
    unsigned int r = (u + 0x7FFFu + ((u >> 16) & 1u)) >> 16;
    return (unsigned short)r;
}

// C = A(MxK) @ W(KxN) + bias
// LAYOUT 0: f32 C[m*N + c]
// LAYOUT 1: bf16 C[((b*HN+h)*NQ + n)*64 + d]       (head-major)
// LAYOUT 2: bf16 C[((b*HN+h)*64 + d)*NQ + n]       (head-major, transposed)
template<int LAYOUT>
__global__ __launch_bounds__(256)
void gemm_f32(const float* __restrict__ A, const float* __restrict__ W,
              const float* __restrict__ bias, void* __restrict__ C,
              int M, int N, int K)
{
    __shared__ float As[16][65];
    __shared__ float Bs[16][64];
    const int tid = threadIdx.x;
    const int bm = blockIdx.y * 64;
    const int bn = blockIdx.x * 64;
    const int tx = tid & 15, ty = tid >> 4;
    float acc[4][4] = {};
    for (int k0 = 0; k0 < K; k0 += 16) {
        #pragma unroll
        for (int l = 0; l < 4; ++l) {
            int idx = tid + l * 256;
            int r = idx >> 4, kk = idx & 15;
            As[kk][r] = A[(size_t)(bm + r) * K + k0 + kk];
        }
        #pragma unroll
        for (int l = 0; l < 4; ++l) {
            int idx = tid + l * 256;
            int kk = idx >> 6, c = idx & 63;
            Bs[kk][c] = W[(size_t)(k0 + kk) * N + bn + c];
        }
        __syncthreads();
        #pragma unroll
        for (int kk = 0; kk < 16; ++kk) {
            float a[4], b[4];
            #pragma unroll
            for (int i = 0; i < 4; ++i) a[i] = As[kk][ty * 4 + i];
            #pragma unroll
            for (int j = 0; j < 4; ++j) b[j] = Bs[kk][tx * 4 + j];
            #pragma unroll
            for (int i = 0; i < 4; ++i)
                #pragma unroll
                for (int j = 0; j < 4; ++j)
                    acc[i][j] += a[i] * b[j];
        }
        __syncthreads();
    }
    #pragma unroll
    for (int i = 0; i < 4; ++i) {
        int m = bm + ty * 4 + i;
        #pragma unroll
        for (int j = 0; j < 4; ++j) {
            int cc = bn + tx * 4 + j;
            float val = acc[i][j] + bias[cc];
            if (LAYOUT == 0) {
                ((float*)C)[(size_t)m * N + cc] = val;
            } else {
                int bb = m >> 10, n = m & (NQ - 1);
                int hh = cc >> 6, d = cc & 63;
                if (LAYOUT == 1)
                    ((unsigned short*)C)[(((size_t)bb * HN + hh) * NQ + n) * DHEAD + d] = f2bf(val);
                else
                    ((unsigned short*)C)[(((size_t)bb * HN + hh) * DHEAD + d) * NQ + n] = f2bf(val);
            }
        }
    }
}

// Tiled MFMA flash-style attention.
// Block: 256 threads = 4 waves; one (b,h), 64 queries (wave w -> 16 queries).
// K-tiles of 64 keys, online softmax, P via wave-private LDS round-trip.
__global__ __launch_bounds__(256)
void attn_mfma(const unsigned short* __restrict__ qws,
               const unsigned short* __restrict__ kws,
               const unsigned short* __restrict__ vtws,
               const float* __restrict__ aw, const int* __restrict__ mask,
               const float* __restrict__ lm, float* __restrict__ out)
{
    const int qt = blockIdx.x, h = blockIdx.y, b = blockIdx.z;
    const int tid = threadIdx.x;
    const int w = tid >> 6, lane = tid & 63;
    const int c = lane & 15, g = lane >> 4;

    __shared__ unsigned short Qs[64 * 64];
    __shared__ unsigned short Ks[64 * 64];
    __shared__ unsigned short Vs[64 * 64];   // Vt tile: rows = d, cols = keys
    __shared__ unsigned short Ps[4][16 * 64];
    __shared__ float lms[NQ];

    const size_t bh = (size_t)b * HN + h;
    const unsigned short* qbase = qws + (bh * NQ + (size_t)qt * 64) * DHEAD;
    const unsigned short* kbase = kws + bh * NQ * DHEAD;
    const unsigned short* vtbase = vtws + bh * DHEAD * NQ;

    // stage Q (swizzled) + lm row
    #pragma unroll
    for (int it = 0; it < 2; ++it) {
        int idx = tid + it * 256, r = idx >> 3, blk = idx & 7;
        *(uint4*)&Qs[r * 64 + ((blk ^ (r & 7)) << 3)] =
            *(const uint4*)&qbase[r * 64 + blk * 8];
    }
    #pragma unroll
    for (int it = 0; it < 4; ++it) {
        int key = tid + it * 256;
        lms[key] = lm[((size_t)b * NQ + key) * HN + h];
    }
    __syncthreads();

    const int qrow = w * 16 + c;
    const bf16x8 qf0 = *(const bf16x8*)&Qs[qrow * 64 + ((g ^ (c & 7)) << 3)];
    const bf16x8 qf1 = *(const bf16x8*)&Qs[qrow * 64 + (((g | 4) ^ (c & 7)) << 3)];

    f32x4 O[4] = {{0,0,0,0},{0,0,0,0},{0,0,0,0},{0,0,0,0}};
    float mrun[4], lrun[4];
    #pragma unroll
    for (int j = 0; j < 4; ++j) { mrun[j] = -1e30f; lrun[j] = 0.f; }

    size_t awrow[4];
    #pragma unroll
    for (int j = 0; j < 4; ++j)
        awrow[j] = (bh * NQ + (size_t)(qt * 64 + w * 16 + 4 * g + j)) * (size_t)NQ;

    for (int kt = 0; kt < 16; ++kt) {
        const int k0 = kt * 64;
        // prefetch aw/mask for this tile (independent of LDS)
        float awv[4][4]; int mkv[4][4];
        #pragma unroll
        for (int nt = 0; nt < 4; ++nt)
            #pragma unroll
            for (int j = 0; j < 4; ++j) {
                size_t idx = awrow[j] + k0 + nt * 16 + c;
                awv[nt][j] = aw[idx];
                mkv[nt][j] = mask[idx];
            }
        __syncthreads();
        #pragma unroll
        for (int it = 0; it < 2; ++it) {
            int idx = tid + it * 256, r = idx >> 3, blk = idx & 7;
            int sw = r * 64 + ((blk ^ (r & 7)) << 3);
            *(uint4*)&Ks[sw] = *(const uint4*)&kbase[(size_t)(k0 + r) * DHEAD + blk * 8];
            *(uint4*)&Vs[sw] = *(const uint4*)&vtbase[(size_t)r * NQ + k0 + blk * 8];
        }
        __syncthreads();

        // S = Q K^T  (16q x 64k per wave)
        f32x4 s[4] = {{0,0,0,0},{0,0,0,0},{0,0,0,0},{0,0,0,0}};
        #pragma unroll
        for (int kk = 0; kk < 2; ++kk) {
            bf16x8 qf = kk ? qf1 : qf0;
            #pragma unroll
            for (int nt = 0; nt < 4; ++nt) {
                int krow = nt * 16 + c;
                bf16x8 kf = *(const bf16x8*)&Ks[krow * 64 + ((((kk << 2) | g) ^ (c & 7)) << 3)];
                s[nt] = __builtin_amdgcn_mfma_f32_16x16x32_bf16(qf, kf, s[nt], 0, 0, 0);
            }
        }

        // scores -> online softmax
        float p[4][4], tmax[4];
        #pragma unroll
        for (int j = 0; j < 4; ++j) tmax[j] = -INFINITY;
        #pragma unroll
        for (int nt = 0; nt < 4; ++nt) {
            float lmv = lms[k0 + nt * 16 + c];
            #pragma unroll
            for (int j = 0; j < 4; ++j) {
                float v = s[nt][j] * 0.125f * awv[nt][j];
                v = mkv[nt][j] ? -INFINITY : v;
                v += lmv;
                p[nt][j] = v;
                tmax[j] = fmaxf(tmax[j], v);
            }
        }
        #pragma unroll
        for (int off = 1; off < 16; off <<= 1)
            #pragma unroll
            for (int j = 0; j < 4; ++j)
                tmax[j] = fmaxf(tmax[j], __shfl_xor(tmax[j], off));

        float mn[4], scal[4], rs[4];
        #pragma unroll
        for (int j = 0; j < 4; ++j) {
            mn[j] = fmaxf(mrun[j], tmax[j]);
            scal[j] = __expf(mrun[j] - mn[j]);
            mrun[j] = mn[j];
            rs[j] = 0.f;
        }
        #pragma unroll
        for (int nt = 0; nt < 4; ++nt)
            #pragma unroll
            for (int j = 0; j < 4; ++j) {
                float e = __expf(p[nt][j] - mn[j]);
                p[nt][j] = e;
                rs[j] += e;
            }
        #pragma unroll
        for (int off = 1; off < 16; off <<= 1)
            #pragma unroll
            for (int j = 0; j < 4; ++j)
                rs[j] += __shfl_xor(rs[j], off);
        #pragma unroll
        for (int j = 0; j < 4; ++j) lrun[j] = lrun[j] * scal[j] + rs[j];
        #pragma unroll
        for (int nd = 0; nd < 4; ++nd)
            #pragma unroll
            for (int j = 0; j < 4; ++j) O[nd][j] *= scal[j];

        // P -> wave-private LDS (bf16, swizzled), re-read in A-fragment layout
        unsigned short* pw = &Ps[w][0];
        #pragma unroll
        for (int nt = 0; nt < 4; ++nt)
            #pragma unroll
            for (int j = 0; j < 4; ++j) {
                int row = 4 * g + j, col = nt * 16 + c;
                pw[row * 64 + (((col >> 3) ^ (row & 7)) << 3) + (col & 7)] = f2bf(p[nt][j]);
            }
        // O += P V
        #pragma unroll
        for (int kk = 0; kk < 2; ++kk) {
            bf16x8 pa = *(const bf16x8*)&pw[c * 64 + ((((kk << 2) | g) ^ (c & 7)) << 3)];
            #pragma unroll
            for (int nd = 0; nd < 4; ++nd) {
                int vrow = nd * 16 + c;
                bf16x8 vf = *(const bf16x8*)&Vs[vrow * 64 + ((((kk << 2) | g) ^ (c & 7)) << 3)];
                O[nd] = __builtin_amdgcn_mfma_f32_16x16x32_bf16(pa, vf, O[nd], 0, 0, 0);
            }
        }
    }

    // epilogue: normalize + store f32 row-major (b, n, h*64+d)
    #pragma unroll
    for (int j = 0; j < 4; ++j) {
        float inv = 1.f / lrun[j];
        int qglob = qt * 64 + w * 16 + 4 * g + j;
        size_t ob = ((size_t)b * NQ + qglob) * DMODEL + h * DHEAD;
        #pragma unroll
        for (int nd = 0; nd < 4; ++nd)
            out[ob + nd * 16 + c] = O[nd][j] * inv;
    }
}

extern "C" void kernel_launch(void* const* d_in, const int* in_sizes, int n_in,
                              void* d_out, int out_size, void* d_ws, size_t ws_size,
                              hipStream_t stream)
{
    const float* queries = (const float*)d_in[0];
    const float* keys    = (const float*)d_in[1];
    const float* values  = (const float*)d_in[2];
    const float* lossmap = (const float*)d_in[3];
    const int*   mask    = (const int*)d_in[4];
    const float* aw      = (const float*)d_in[5];
    const float* Wq = (const float*)d_in[6];
    const float* bq = (const float*)d_in[7];
    const float* Wk = (const float*)d_in[8];
    const float* bk = (const float*)d_in[9];
    const float* Wv = (const float*)d_in[10];
    const float* bv = (const float*)d_in[11];
    const float* Wo = (const float*)d_in[12];
    const float* bo = (const float*)d_in[13];

    const size_t PER = (size_t)NB * HN * NQ * DHEAD;  // 3,145,728 elements
    unsigned short* qws  = (unsigned short*)d_ws;
    unsigned short* kws  = qws + PER;
    unsigned short* vtws = kws + PER;
    float* ows = (float*)(vtws + PER);

    const int M = NB * NQ;  // 4096
    dim3 gg(DMODEL / 64, M / 64), gb(256);
    gemm_f32<1><<<gg, gb, 0, stream>>>(queries, Wq, bq, qws,  M, DMODEL, DMODEL);
    gemm_f32<1><<<gg, gb, 0, stream>>>(keys,    Wk, bk, kws,  M, DMODEL, DMODEL);
    gemm_f32<2><<<gg, gb, 0, stream>>>(values,  Wv, bv, vtws, M, DMODEL, DMODEL);
    attn_mfma<<<dim3(NQ / 64, HN, NB), 256, 0, stream>>>(qws, kws, vtws, aw, mask, lossmap, ows);
    gemm_f32<0><<<gg, gb, 0, stream>>>(ows, Wo, bo, d_out, M, DMODEL, DMODEL);
}

// Round 3
// 197.680 us; speedup vs baseline: 16.3915x; 2.7444x over previous
//
#include <hip/hip_runtime.h>
#include <hip/hip_bf16.h>
#include <cmath>

static constexpr int HN = 12;      // heads
static constexpr int DHEAD = 64;   // head dim
static constexpr int DMODEL = 768;
static constexpr int NQ = 1024;    // seq len (q == k)
static constexpr int NB = 4;       // batch
static constexpr int MROWS = NB * NQ;        // 4096
static constexpr size_t PER = (size_t)NB * HN * NQ * DHEAD;  // 3,145,728
static constexpr size_t WN  = (size_t)DMODEL * DMODEL;       // 589,824

typedef __attribute__((ext_vector_type(8))) short bf16x8;
typedef __attribute__((ext_vector_type(4))) float f32x4;

static __device__ __forceinline__ unsigned short f2bf(float f) {
    unsigned int u = __builtin_bit_cast(unsigned int, f);
    unsigned int r = (u + 0x7FFFu + ((u >> 16) & 1u)) >> 16;
    return (unsigned short)r;
}

// async global->LDS, 16B per lane; LDS dest must be wave-uniform base.
typedef const __attribute__((address_space(1))) unsigned int gu32;
typedef __attribute__((address_space(3))) unsigned int lu32;
static __device__ __forceinline__ void gload16(const void* g, void* l) {
    __builtin_amdgcn_global_load_lds((gu32*)g, (lu32*)l, 16, 0, 0);
}

// ---------- converts ----------
__global__ __launch_bounds__(256)
void cvt3(const float* __restrict__ a, const float* __restrict__ b, const float* __restrict__ c,
          unsigned short* __restrict__ oa, unsigned short* __restrict__ ob, unsigned short* __restrict__ oc)
{
    const int z = blockIdx.z;
    const float* s = z == 0 ? a : z == 1 ? b : c;
    unsigned short* d = z == 0 ? oa : z == 1 ? ob : oc;
    size_t i = ((size_t)blockIdx.x * 256 + threadIdx.x) * 4;
    float4 v = *(const float4*)&s[i];
    ushort4 u;
    u.x = f2bf(v.x); u.y = f2bf(v.y); u.z = f2bf(v.z); u.w = f2bf(v.w);
    *(ushort4*)&d[i] = u;
}

// W[k][n] f32 -> Wt[n][k] bf16 (768x768 per tensor)
__global__ __launch_bounds__(256)
void wtrans(const float* __restrict__ w0, const float* __restrict__ w1,
            const float* __restrict__ w2, const float* __restrict__ w3,
            unsigned short* __restrict__ o0, unsigned short* __restrict__ o1,
            unsigned short* __restrict__ o2, unsigned short* __restrict__ o3)
{
    const int z = blockIdx.z;
    const float* in = z == 0 ? w0 : z == 1 ? w1 : z == 2 ? w2 : w3;
    unsigned short* out = z == 0 ? o0 : z == 1 ? o1 : z == 2 ? o2 : o3;
    __shared__ float t[64][65];
    const int tid = threadIdx.x;
    const int k0 = blockIdx.x * 64, n0 = blockIdx.y * 64;
    #pragma unroll
    for (int l = 0; l < 16; ++l) {
        int idx = l * 256 + tid, r = idx >> 6, cc = idx & 63;
        t[r][cc] = in[(size_t)(k0 + r) * DMODEL + n0 + cc];
    }
    __syncthreads();
    #pragma unroll
    for (int l = 0; l < 16; ++l) {
        int idx = l * 256 + tid, r = idx >> 6, cc = idx & 63;
        out[(size_t)(n0 + r) * DMODEL + k0 + cc] = f2bf(t[cc][r]);
    }
}

// ---------- bf16 MFMA GEMM (128x128 tile, BK=64, 4 waves, gload_lds staging) ----------
// A: [M][K] bf16 (M=4096, K=768).  Wt: [N][K] bf16 (N=768).  bias f32.
// layout 1: bf16 C[((bb*HN+hh)*NQ+nn)*64+d]
// layout 2: bf16 C[((bb*HN+hh)*64+d)*NQ+nn]
// layout 0: f32  C[m*N+col]
static __device__ __forceinline__
void gemm_body(const unsigned short* __restrict__ A, const unsigned short* __restrict__ Wt,
               const float* __restrict__ bias, void* __restrict__ C, int layout)
{
    constexpr int K = DMODEL;
    __shared__ unsigned short As[128 * 64];
    __shared__ unsigned short Bs[128 * 64];
    const int tid = threadIdx.x, w = tid >> 6, lane = tid & 63;
    const int c = lane & 15, g = lane >> 4;
    const int wr = w >> 1, wc = w & 1;
    const int bn = blockIdx.x * 128, bm = blockIdx.y * 128;

    f32x4 acc[4][4] = {};
    for (int k0 = 0; k0 < K; k0 += 64) {
        #pragma unroll
        for (int it = 0; it < 4; ++it) {
            int idx = it * 256 + tid, r = idx >> 3, blk = idx & 7;
            int so = (blk ^ (r & 7)) << 3;
            gload16(A  + (size_t)(bm + r) * K + k0 + so, &As[(it * 256 + w * 64) * 8]);
            gload16(Wt + (size_t)(bn + r) * K + k0 + so, &Bs[(it * 256 + w * 64) * 8]);
        }
        __syncthreads();
        #pragma unroll
        for (int kk = 0; kk < 2; ++kk) {
            bf16x8 a[4], b[4];
            #pragma unroll
            for (int mi = 0; mi < 4; ++mi) {
                int row = wr * 64 + mi * 16 + c;
                a[mi] = *(const bf16x8*)&As[row * 64 + ((((kk << 2) | g) ^ (row & 7)) << 3)];
            }
            #pragma unroll
            for (int ni = 0; ni < 4; ++ni) {
                int row = wc * 64 + ni * 16 + c;
                b[ni] = *(const bf16x8*)&Bs[row * 64 + ((((kk << 2) | g) ^ (row & 7)) << 3)];
            }
            #pragma unroll
            for (int mi = 0; mi < 4; ++mi)
                #pragma unroll
                for (int ni = 0; ni < 4; ++ni)
                    acc[mi][ni] = __builtin_amdgcn_mfma_f32_16x16x32_bf16(a[mi], b[ni], acc[mi][ni], 0, 0, 0);
        }
        __syncthreads();
    }

    #pragma unroll
    for (int ni = 0; ni < 4; ++ni) {
        int col = bn + wc * 64 + ni * 16 + c;
        float bvx = bias[col];
        int hh = col >> 6, d = col & 63;
        #pragma unroll
        for (int mi = 0; mi < 4; ++mi) {
            int m0 = bm + wr * 64 + mi * 16 + 4 * g;
            int bb = m0 >> 10, nn0 = m0 & (NQ - 1);
            if (layout == 0) {
                float* o = (float*)C;
                #pragma unroll
                for (int j = 0; j < 4; ++j)
                    o[(size_t)(m0 + j) * DMODEL + col] = acc[mi][ni][j] + bvx;
            } else if (layout == 1) {
                unsigned short* o = (unsigned short*)C;
                #pragma unroll
                for (int j = 0; j < 4; ++j)
                    o[(((size_t)bb * HN + hh) * NQ + nn0 + j) * DHEAD + d] =
                        f2bf(acc[mi][ni][j] + bvx);
            } else {
                unsigned short* o = (unsigned short*)C;
                ushort4 u;
                u.x = f2bf(acc[mi][ni][0] + bvx);
                u.y = f2bf(acc[mi][ni][1] + bvx);
                u.z = f2bf(acc[mi][ni][2] + bvx);
                u.w = f2bf(acc[mi][ni][3] + bvx);
                *(ushort4*)&o[(((size_t)bb * HN + hh) * DHEAD + d) * NQ + nn0] = u;
            }
        }
    }
}

__global__ __launch_bounds__(256)
void qkv_gemm(const unsigned short* __restrict__ qa, const unsigned short* __restrict__ ka,
              const unsigned short* __restrict__ va,
              const unsigned short* __restrict__ wq, const unsigned short* __restrict__ wk,
              const unsigned short* __restrict__ wv,
              const float* __restrict__ bq, const float* __restrict__ bk, const float* __restrict__ bv,
              unsigned short* __restrict__ qo, unsigned short* __restrict__ ko,
              unsigned short* __restrict__ vo)
{
    const int z = blockIdx.z;
    const unsigned short* A  = z == 0 ? qa : z == 1 ? ka : va;
    const unsigned short* Wt = z == 0 ? wq : z == 1 ? wk : wv;
    const float* bias        = z == 0 ? bq : z == 1 ? bk : bv;
    unsigned short* C        = z == 0 ? qo : z == 1 ? ko : vo;
    gemm_body(A, Wt, bias, C, z == 2 ? 2 : 1);
}

__global__ __launch_bounds__(256)
void o_gemm(const unsigned short* __restrict__ A, const unsigned short* __restrict__ Wt,
            const float* __restrict__ bias, float* __restrict__ C)
{
    gemm_body(A, Wt, bias, C, 0);
}

// ---------- attention ----------
// Block: 256 threads = 4 waves; one (b,h), 64 queries. Double-buffered K/V LDS,
// one barrier per K-tile, aw/mask register prefetch one tile ahead.
__global__ __launch_bounds__(256)
void attn_mfma(const unsigned short* __restrict__ qws,
               const unsigned short* __restrict__ kws,
               const unsigned short* __restrict__ vtws,
               const float* __restrict__ aw, const int* __restrict__ mask,
               const float* __restrict__ lm, unsigned short* __restrict__ out)
{
    const int qt = blockIdx.x, h = blockIdx.y, b = blockIdx.z;
    const int tid = threadIdx.x;
    const int w = tid >> 6, lane = tid & 63;
    const int c = lane & 15, g = lane >> 4;

    __shared__ unsigned short Qs[64 * 64];
    __shared__ unsigned short Ks[2][64 * 64];
    __shared__ unsigned short Vs[2][64 * 64];
    __shared__ unsigned short Ps[4][16 * 64];
    __shared__ float lms[NQ];

    const size_t bh = (size_t)b * HN + h;
    const unsigned short* qbase = qws + (bh * NQ + (size_t)qt * 64) * DHEAD;
    const unsigned short* kbase = kws + bh * NQ * DHEAD;
    const unsigned short* vtbase = vtws + bh * DHEAD * NQ;

    // stage Q (linear LDS, pre-swizzled source)
    #pragma unroll
    for (int it = 0; it < 2; ++it) {
        int idx = it * 256 + tid, r = idx >> 3, blk = idx & 7;
        gload16(qbase + (size_t)r * DHEAD + ((blk ^ (r & 7)) << 3),
                &Qs[(it * 256 + w * 64) * 8]);
    }
    #pragma unroll
    for (int it = 0; it < 4; ++it) {
        int key = it * 256 + tid;
        lms[key] = lm[((size_t)b * NQ + key) * HN + h];
    }

    size_t awrow[4];
    #pragma unroll
    for (int j = 0; j < 4; ++j)
        awrow[j] = (bh * NQ + (size_t)(qt * 64 + w * 16 + 4 * g + j)) * (size_t)NQ;

    auto stageKV = [&](int kt, int bufi) {
        const int k0 = kt * 64;
        #pragma unroll
        for (int it = 0; it < 2; ++it) {
            int idx = it * 256 + tid, r = idx >> 3, blk = idx & 7;
            int so = (blk ^ (r & 7)) << 3;
            gload16(kbase + (size_t)(k0 + r) * DHEAD + so, &Ks[bufi][(it * 256 + w * 64) * 8]);
            gload16(vtbase + (size_t)r * NQ + k0 + so,     &Vs[bufi][(it * 256 + w * 64) * 8]);
        }
    };

    float awv[4][4]; int mkv[4][4];
    #pragma unroll
    for (int nt = 0; nt < 4; ++nt)
        #pragma unroll
        for (int j = 0; j < 4; ++j) {
            size_t idx = awrow[j] + nt * 16 + c;
            awv[nt][j] = aw[idx];
            mkv[nt][j] = mask[idx];
        }
    stageKV(0, 0);
    __syncthreads();

    const int qrow = w * 16 + c;
    const bf16x8 qf0 = *(const bf16x8*)&Qs[qrow * 64 + ((g ^ (c & 7)) << 3)];
    const bf16x8 qf1 = *(const bf16x8*)&Qs[qrow * 64 + (((g | 4) ^ (c & 7)) << 3)];

    f32x4 O[4] = {{0,0,0,0},{0,0,0,0},{0,0,0,0},{0,0,0,0}};
    float mrun[4], lrun[4];
    #pragma unroll
    for (int j = 0; j < 4; ++j) { mrun[j] = -1e30f; lrun[j] = 0.f; }

    #pragma unroll 2
    for (int kt = 0; kt < 16; ++kt) {
        const int cur = kt & 1;
        const int k0 = kt * 64;
        float awn[4][4]; int mkn[4][4];
        if (kt < 15) {
            stageKV(kt + 1, cur ^ 1);
            #pragma unroll
            for (int nt = 0; nt < 4; ++nt)
                #pragma unroll
                for (int j = 0; j < 4; ++j) {
                    size_t idx = awrow[j] + (kt + 1) * 64 + nt * 16 + c;
                    awn[nt][j] = aw[idx];
                    mkn[nt][j] = mask[idx];
                }
        }
        const unsigned short* ksb = &Ks[cur][0];
        const unsigned short* vsb = &Vs[cur][0];

        // S = Q K^T
        f32x4 s[4] = {{0,0,0,0},{0,0,0,0},{0,0,0,0},{0,0,0,0}};
        #pragma unroll
        for (int kk = 0; kk < 2; ++kk) {
            bf16x8 qf = kk ? qf1 : qf0;
            #pragma unroll
            for (int nt = 0; nt < 4; ++nt) {
                int krow = nt * 16 + c;
                bf16x8 kf = *(const bf16x8*)&ksb[krow * 64 + ((((kk << 2) | g) ^ (c & 7)) << 3)];
                s[nt] = __builtin_amdgcn_mfma_f32_16x16x32_bf16(qf, kf, s[nt], 0, 0, 0);
            }
        }

        // online softmax
        float p[4][4], tmax[4];
        #pragma unroll
        for (int j = 0; j < 4; ++j) tmax[j] = -INFINITY;
        #pragma unroll
        for (int nt = 0; nt < 4; ++nt) {
            float lmv = lms[k0 + nt * 16 + c];
            #pragma unroll
            for (int j = 0; j < 4; ++j) {
                float v = s[nt][j] * 0.125f * awv[nt][j];
                v = mkv[nt][j] ? -INFINITY : v;
                v += lmv;
                p[nt][j] = v;
                tmax[j] = fmaxf(tmax[j], v);
            }
        }
        #pragma unroll
        for (int off = 1; off < 16; off <<= 1)
            #pragma unroll
            for (int j = 0; j < 4; ++j)
                tmax[j] = fmaxf(tmax[j], __shfl_xor(tmax[j], off));

        float mn[4], scal[4], rs[4];
        #pragma unroll
        for (int j = 0; j < 4; ++j) {
            mn[j] = fmaxf(mrun[j], tmax[j]);
            scal[j] = __expf(mrun[j] - mn[j]);
            mrun[j] = mn[j];
            rs[j] = 0.f;
        }
        #pragma unroll
        for (int nt = 0; nt < 4; ++nt)
            #pragma unroll
            for (int j = 0; j < 4; ++j) {
                float e = __expf(p[nt][j] - mn[j]);
                p[nt][j] = e;
                rs[j] += e;
            }
        #pragma unroll
        for (int off = 1; off < 16; off <<= 1)
            #pragma unroll
            for (int j = 0; j < 4; ++j)
                rs[j] += __shfl_xor(rs[j], off);
        #pragma unroll
        for (int j = 0; j < 4; ++j) lrun[j] = lrun[j] * scal[j] + rs[j];
        #pragma unroll
        for (int nd = 0; nd < 4; ++nd)
            #pragma unroll
            for (int j = 0; j < 4; ++j) O[nd][j] *= scal[j];

        // P -> wave-private LDS (bf16, swizzled), re-read as A fragment
        unsigned short* pw = &Ps[w][0];
        #pragma unroll
        for (int nt = 0; nt < 4; ++nt)
            #pragma unroll
            for (int j = 0; j < 4; ++j) {
                int row = 4 * g + j, col = nt * 16 + c;
                pw[row * 64 + (((col >> 3) ^ (row & 7)) << 3) + (col & 7)] = f2bf(p[nt][j]);
            }
        #pragma unroll
        for (int kk = 0; kk < 2; ++kk) {
            bf16x8 pa = *(const bf16x8*)&pw[c * 64 + ((((kk << 2) | g) ^ (c & 7)) << 3)];
            #pragma unroll
            for (int nd = 0; nd < 4; ++nd) {
                int vrow = nd * 16 + c;
                bf16x8 vf = *(const bf16x8*)&vsb[vrow * 64 + ((((kk << 2) | g) ^ (c & 7)) << 3)];
                O[nd] = __builtin_amdgcn_mfma_f32_16x16x32_bf16(pa, vf, O[nd], 0, 0, 0);
            }
        }
        __syncthreads();   // drains staged loads (vmcnt 0) + protects buffer swap
        if (kt < 15) {
            #pragma unroll
            for (int nt = 0; nt < 4; ++nt)
                #pragma unroll
                for (int j = 0; j < 4; ++j) { awv[nt][j] = awn[nt][j]; mkv[nt][j] = mkn[nt][j]; }
        }
    }

    // epilogue: normalize + store bf16 row-major (b, n, h*64+d)
    #pragma unroll
    for (int j = 0; j < 4; ++j) {
        float inv = 1.f / lrun[j];
        int qglob = qt * 64 + w * 16 + 4 * g + j;
        size_t ob = ((size_t)b * NQ + qglob) * DMODEL + h * DHEAD;
        #pragma unroll
        for (int nd = 0; nd < 4; ++nd)
            out[ob + nd * 16 + c] = f2bf(O[nd][j] * inv);
    }
}

extern "C" void kernel_launch(void* const* d_in, const int* in_sizes, int n_in,
                              void* d_out, int out_size, void* d_ws, size_t ws_size,
                              hipStream_t stream)
{
    const float* queries = (const float*)d_in[0];
    const float* keys    = (const float*)d_in[1];
    const float* values  = (const float*)d_in[2];
    const float* lossmap = (const float*)d_in[3];
    const int*   mask    = (const int*)d_in[4];
    const float* aw      = (const float*)d_in[5];
    const float* Wq = (const float*)d_in[6];
    const float* bq = (const float*)d_in[7];
    const float* Wk = (const float*)d_in[8];
    const float* bk = (const float*)d_in[9];
    const float* Wv = (const float*)d_in[10];
    const float* bv = (const float*)d_in[11];
    const float* Wo = (const float*)d_in[12];
    const float* bo = (const float*)d_in[13];

    unsigned short* p = (unsigned short*)d_ws;
    unsigned short* qbf  = p; p += PER;
    unsigned short* kbf  = p; p += PER;
    unsigned short* vbf  = p; p += PER;
    unsigned short* qws  = p; p += PER;
    unsigned short* kws  = p; p += PER;
    unsigned short* vtws = p; p += PER;
    unsigned short* aobf = p; p += PER;
    unsigned short* wqt  = p; p += WN;
    unsigned short* wkt  = p; p += WN;
    unsigned short* wvt  = p; p += WN;
    unsigned short* wot  = p; p += WN;

    cvt3<<<dim3((unsigned)(PER / 1024), 1, 3), 256, 0, stream>>>(queries, keys, values, qbf, kbf, vbf);
    wtrans<<<dim3(12, 12, 4), 256, 0, stream>>>(Wq, Wk, Wv, Wo, wqt, wkt, wvt, wot);
    qkv_gemm<<<dim3(DMODEL / 128, MROWS / 128, 3), 256, 0, stream>>>(
        qbf, kbf, vbf, wqt, wkt, wvt, bq, bk, bv, qws, kws, vtws);
    attn_mfma<<<dim3(NQ / 64, HN, NB), 256, 0, stream>>>(qws, kws, vtws, aw, mask, lossmap, aobf);
    o_gemm<<<dim3(DMODEL / 128, MROWS / 128), 256, 0, stream>>>(aobf, wot, bo, (float*)d_out);
}